// Round 12
// baseline (189.505 us; speedup 1.0000x reference)
//
#include <hip/hip_runtime.h>
#include <math.h>

#define S_LEN 2048
#define BATCH 2
#define DMODEL 1024
#define NHEADS 16
#define MROWS 4096

typedef short bf8 __attribute__((ext_vector_type(8)));   // 8 x bf16
typedef short bf4 __attribute__((ext_vector_type(4)));   // 4 x bf16
typedef float f32x4 __attribute__((ext_vector_type(4))); // 16x16 MFMA acc
typedef float f32x16 __attribute__((ext_vector_type(16))); // 32x32 MFMA acc
typedef unsigned short u16;

static __device__ inline u16 f2bf(float f) {
    union { float f; unsigned u; } v; v.f = f;
    unsigned r = v.u + 0x7fffu + ((v.u >> 16) & 1u); // RNE
    return (u16)(r >> 16);
}

// async global->LDS DMA, 16B per lane. LDS dest = (wave-uniform base) + lane*16.
static __device__ inline void load16(const void* g, void* l) {
    __builtin_amdgcn_global_load_lds(
        (const __attribute__((address_space(1))) unsigned int*)g,
        (__attribute__((address_space(3))) unsigned int*)l, 16, 0, 0);
}

// ---------------------------------------------------------------------------
// Fused prep (frozen): blocks [0,2048) convert x fp32->bf16; [2048,3072)
// transpose the 4 weights to Wt[n][k] bf16.
// ---------------------------------------------------------------------------
__global__ __launch_bounds__(256) void prep_kernel(
    const float* __restrict__ x, u16* __restrict__ xb,
    const float* __restrict__ W0, const float* __restrict__ W1,
    const float* __restrict__ W2, const float* __restrict__ W3,
    u16* __restrict__ wT) {
    const int bx = blockIdx.x, t = threadIdx.x;
    if (bx < 2048) {
        int i = bx * 256 + t;
        const float4* p = (const float4*)x + (size_t)i * 2;
        float4 a = p[0], b = p[1];
        u16 tmp[8] = {f2bf(a.x), f2bf(a.y), f2bf(a.z), f2bf(a.w),
                      f2bf(b.x), f2bf(b.y), f2bf(b.z), f2bf(b.w)};
        ((uint4*)xb)[i] = *(uint4*)tmp;
        return;
    }
    __shared__ u16 Ls[64][65];
    const int id = bx - 2048;
    const int z = id >> 8, rem = id & 255;
    const int n0 = (rem & 15) * 64, k0 = (rem >> 4) * 64;
    const float* W = z == 0 ? W0 : z == 1 ? W1 : z == 2 ? W2 : W3;
    u16* Wt = wT + (size_t)z * 1024 * 1024;
    const int r = t >> 2, c4 = (t & 3) * 16;
    const float* p = W + (size_t)(k0 + r) * 1024 + n0 + c4;
#pragma unroll
    for (int i = 0; i < 16; i += 4) {
        float4 v = *(const float4*)(p + i);
        Ls[r][c4 + i + 0] = f2bf(v.x);
        Ls[r][c4 + i + 1] = f2bf(v.y);
        Ls[r][c4 + i + 2] = f2bf(v.z);
        Ls[r][c4 + i + 3] = f2bf(v.w);
    }
    __syncthreads();
    u16 tmp[16];
#pragma unroll
    for (int i = 0; i < 16; i++) tmp[i] = Ls[c4 + i][r];
    uint4* q = (uint4*)(Wt + (size_t)(n0 + r) * 1024 + k0 + c4);
    q[0] = *(uint4*)tmp;
    q[1] = *(uint4*)(tmp + 8);
}

// ---------------------------------------------------------------------------
// QKV GEMM (frozen, R9/R11-verified): m97 single-buffered 128x128, BK=64,
// global_load_lds staging, XOR-swizzled source + swizzled ds_read_b128.
// MODE 0: QKV (grid 24x32): sect 0->Q bf16*qscale, 1->K bf16, 2->V^T scatter
// ---------------------------------------------------------------------------
template <int MODE>
__global__ __launch_bounds__(256) void gemm_mfma(
    const u16* __restrict__ A, const u16* __restrict__ Bt,
    const float* __restrict__ bqp, const float* __restrict__ bkp,
    const float* __restrict__ bvp,
    u16* __restrict__ qout, u16* __restrict__ kout, u16* __restrict__ vtout,
    float* __restrict__ fout, float qscale) {
    __shared__ __align__(16) u16 As[128 * 64]; // x rows    [row][k] swizzled
    __shared__ __align__(16) u16 Bs[128 * 64]; // features  [row][k] swizzled

    const int t = threadIdx.x, lane = t & 63, w = t >> 6;
    const int quad = lane >> 4, l16 = lane & 15;
    const int wr = w >> 1, wc = w & 1; // wave quadrant: rows wr*64, cols wc*64
    const int row0 = blockIdx.y * 128, col0 = blockIdx.x * 128;
    const int K = DMODEL;

    const int srow = t >> 3;                    // 0..31
    const int ksw = ((t & 7) ^ (srow & 7)) * 8; // swizzled k offset (u16)
    const u16* ag = A + (size_t)(row0 + srow) * K + ksw;
    const u16* bg = Bt + (size_t)(col0 + srow) * K + ksw;
    const int swz = l16 & 7;

    f32x4 acc[4][4] = {}; // [mi=col frag][ni=row frag]

    u16* lA = As + (size_t)(w * 8) * 64; // wave-uniform DMA dest base
    u16* lB = Bs + (size_t)(w * 8) * 64;

    for (int it = 0; it < 16; ++it) {
        if (it) __syncthreads(); // all waves done reading LDS
        const int k0 = it * 64;
#pragma unroll
        for (int i = 0; i < 4; i++) { // 4 issues x 32 rows each, A and B
            load16(ag + (size_t)i * 32 * K + k0, lA + i * 32 * 64);
            load16(bg + (size_t)i * 32 * K + k0, lB + i * 32 * 64);
        }
        __syncthreads(); // vmcnt(0) drain: DMA landed for all waves
#pragma unroll
        for (int kc = 0; kc < 2; kc++) {
            bf8 xf[4], wf[4];
#pragma unroll
            for (int ni = 0; ni < 4; ni++)
                xf[ni] = *(const bf8*)&As[(wr * 64 + ni * 16 + l16) * 64 +
                                          ((kc * 4 + quad) ^ swz) * 8];
#pragma unroll
            for (int mi = 0; mi < 4; mi++)
                wf[mi] = *(const bf8*)&Bs[(wc * 64 + mi * 16 + l16) * 64 +
                                          ((kc * 4 + quad) ^ swz) * 8];
#pragma unroll
            for (int mi = 0; mi < 4; mi++)
#pragma unroll
                for (int ni = 0; ni < 4; ni++)
                    acc[mi][ni] = __builtin_amdgcn_mfma_f32_16x16x32_bf16(
                        wf[mi], xf[ni], acc[mi][ni], 0, 0, 0);
        }
    }

    const int sect = (col0 + wc * 64) >> 10; // uniform per wave (64-col span)
#pragma unroll
    for (int mi = 0; mi < 4; mi++) {
        const int featb = col0 + wc * 64 + mi * 16 + quad * 4;
        float b4[4];
#pragma unroll
        for (int reg = 0; reg < 4; reg++)
            b4[reg] = (MODE == 1 ? bqp : (sect == 0 ? bqp : sect == 1 ? bkp : bvp))
                          [(featb + reg) & 1023];
#pragma unroll
        for (int ni = 0; ni < 4; ni++) {
            const int xrow = row0 + wr * 64 + ni * 16 + l16;
            if (MODE == 1) {
                float4 o;
                o.x = acc[mi][ni][0] + b4[0];
                o.y = acc[mi][ni][1] + b4[1];
                o.z = acc[mi][ni][2] + b4[2];
                o.w = acc[mi][ni][3] + b4[3];
                *(float4*)(fout + (size_t)xrow * 1024 + featb) = o;
            } else {
                const int cf = featb & 1023;
                if (sect == 0) {
                    u16 t4[4];
#pragma unroll
                    for (int reg = 0; reg < 4; reg++)
                        t4[reg] = f2bf((acc[mi][ni][reg] + b4[reg]) * qscale);
                    *(uint2*)(qout + (size_t)xrow * 1024 + cf) = *(uint2*)t4;
                } else if (sect == 1) {
                    u16 t4[4];
#pragma unroll
                    for (int reg = 0; reg < 4; reg++)
                        t4[reg] = f2bf(acc[mi][ni][reg] + b4[reg]);
                    *(uint2*)(kout + (size_t)xrow * 1024 + cf) = *(uint2*)t4;
                } else { // V^T: Vt[(xrow>>11)*1024 + f][xrow&2047]
#pragma unroll
                    for (int reg = 0; reg < 4; reg++)
                        vtout[((size_t)(xrow >> 11) * 1024 + cf + reg) * S_LEN +
                              (xrow & 2047)] = f2bf(acc[mi][ni][reg] + b4[reg]);
                }
            }
        }
    }
}

// ---------------------------------------------------------------------------
// O-proj GEMM (frozen, R11-verified): 64x128 dbuf tiles, grid 8x64.
// ---------------------------------------------------------------------------
__global__ __launch_bounds__(256) void gemm_oproj(
    const u16* __restrict__ A, const u16* __restrict__ Bt,
    const float* __restrict__ bop, float* __restrict__ fout) {
    __shared__ __align__(16) u16 As[2][64 * 64];  // x rows
    __shared__ __align__(16) u16 Bs[2][128 * 64]; // W rows (features)

    const int t = threadIdx.x, lane = t & 63, w = t >> 6;
    const int quad = lane >> 4, l16 = lane & 15;
    const int row0 = blockIdx.y * 64, col0 = blockIdx.x * 128;
    const int K = DMODEL;

    const int lrow = lane >> 3;               // 0..7
    const int koff = ((lane & 7) ^ lrow) * 8; // swizzled k-group (global side)
    const u16* ag = A + (size_t)(row0 + w * 16 + lrow) * K + koff;
    const u16* bg = Bt + (size_t)(col0 + w * 32 + lrow) * K + koff;
    const int swz = l16 & 7;

    f32x4 acc[2][4] = {};

    // prologue: stage k0=0 into buffer 0
    {
        u16* lA = As[0] + (w * 16) * 64;
        u16* lB = Bs[0] + (w * 32) * 64;
        load16(ag, lA);
        load16(ag + (size_t)8 * K, lA + 512);
#pragma unroll
        for (int d = 0; d < 4; d++)
            load16(bg + (size_t)d * 8 * K, lB + d * 512);
    }

#pragma unroll 2
    for (int it = 0; it < 16; it++) {
        const int buf = it & 1;
        __syncthreads(); // current buf's DMA landed; prior reads of other buf done
        if (it + 1 < 16) { // prefetch next k-slab into the other buffer
            const int k0 = (it + 1) * 64;
            u16* lA = As[buf ^ 1] + (w * 16) * 64;
            u16* lB = Bs[buf ^ 1] + (w * 32) * 64;
            load16(ag + k0, lA);
            load16(ag + (size_t)8 * K + k0, lA + 512);
#pragma unroll
            for (int d = 0; d < 4; d++)
                load16(bg + (size_t)d * 8 * K + k0, lB + d * 512);
        }
#pragma unroll
        for (int kc = 0; kc < 2; kc++) {
            bf8 xf[4], wf[2];
#pragma unroll
            for (int ni = 0; ni < 4; ni++)
                xf[ni] = *(const bf8*)&As[buf][(ni * 16 + l16) * 64 +
                                              ((kc * 4 + quad) ^ swz) * 8];
#pragma unroll
            for (int mi = 0; mi < 2; mi++)
                wf[mi] = *(const bf8*)&Bs[buf][(w * 32 + mi * 16 + l16) * 64 +
                                              ((kc * 4 + quad) ^ swz) * 8];
#pragma unroll
            for (int mi = 0; mi < 2; mi++)
#pragma unroll
                for (int ni = 0; ni < 4; ni++)
                    acc[mi][ni] = __builtin_amdgcn_mfma_f32_16x16x32_bf16(
                        wf[mi], xf[ni], acc[mi][ni], 0, 0, 0);
        }
    }

#pragma unroll
    for (int mi = 0; mi < 2; mi++) {
        const int featb = col0 + w * 32 + mi * 16 + quad * 4;
        float b4[4];
#pragma unroll
        for (int reg = 0; reg < 4; reg++)
            b4[reg] = bop[(featb + reg) & 1023];
#pragma unroll
        for (int ni = 0; ni < 4; ni++) {
            const int xrow = row0 + ni * 16 + l16;
            float4 o;
            o.x = acc[mi][ni][0] + b4[0];
            o.y = acc[mi][ni][1] + b4[1];
            o.z = acc[mi][ni][2] + b4[2];
            o.w = acc[mi][ni][3] + b4[3];
            *(float4*)(fout + (size_t)xrow * 1024 + featb) = o;
        }
    }
}

// ---------------------------------------------------------------------------
// R12 flash attention: 32x32 MFMA restructure (halves LDS-read bytes/FLOP —
// attn was LDS-pipe-bound: 256KB reads per 32KB staged at 16x16 granularity).
// 4 waves x 32 q-rows = 128 q/block; KV tile = 64 keys; grid 32bh x 16pi
// (heavy-first); 2 blocks/CU at 2 waves/SIMD -> 256-reg budget (no wall).
// QK^T: S^T = mfma_32x32x16(K_frag, Q_frag) -> lane: q=lane&31,
//   key=(r&3)+8(r>>2)+4*(lane>>5) per 32-key subtile (C layout m74/m101).
// P stays in-register: v_cvt_pk_bf16_f32 pairs + v_permlane32_swap_b32
// builds the PV B-operand (k=(lane>>5)*8+j) — one swap fills two words for
// both lane halves (T12 recipe, derived & checked against C layout).
// PV: O^T = mfma_32x32x16(V^T_frag, P_frag). K/V staged by dbuf
// global_load_lds, pre-swizzled source slot^(row&7), one barrier/tile (R9).
// ---------------------------------------------------------------------------
__global__ __launch_bounds__(256, 2) void attn_kernel(
    const u16* __restrict__ Qg, const u16* __restrict__ Kg,
    const u16* __restrict__ Vt, u16* __restrict__ Og) {
    // [buf][ K: 64 keys x 64 d | V: 64 d x 64 keys ], each 8KB, swizzled rows
    __shared__ __align__(16) u16 LdsF[2][8192]; // 32KB

    const int t = threadIdx.x, lane = t & 63, w = t >> 6; // 4 waves
    const int l31 = lane & 31, hi = lane >> 5;
    const int pi = 15 - blockIdx.y;            // heavy blocks dispatch first
    const int bh = blockIdx.x, b = bh >> 4, h = bh & 15;
    const size_t base = (size_t)b * S_LEN * DMODEL + h * 64;
    const size_t vbase = ((size_t)b * 1024 + h * 64) * S_LEN;

    // ---- staging: wave w covers K rows [w*16,w*16+16) and V d-rows same ----
    const int sr8 = lane >> 3, sl = lane & 7; // row-within-8, 16B slot 0..7
    const int r0 = w * 16 + sr8, r1 = w * 16 + 8 + sr8;
    const int ko0 = ((sl ^ (r0 & 7)) * 8), ko1 = ((sl ^ (r1 & 7)) * 8);
    const u16* kS0 = Kg + base + (size_t)r0 * DMODEL + ko0;
    const u16* kS1 = Kg + base + (size_t)r1 * DMODEL + ko1;
    const u16* vS0 = Vt + vbase + (size_t)r0 * S_LEN + ko0;
    const u16* vS1 = Vt + vbase + (size_t)r1 * S_LEN + ko1;
    const int dstK = (w * 16) * 64;        // u16, wave-uniform
    const int dstV = 4096 + (w * 16) * 64;

#define STAGE(bs, tile)                                                        \
    {                                                                          \
        const size_t kadv = (size_t)(tile) * 64;                               \
        load16(kS0 + kadv * DMODEL, &LdsF[bs][dstK]);                          \
        load16(kS1 + kadv * DMODEL, &LdsF[bs][dstK + 512]);                    \
        load16(vS0 + kadv, &LdsF[bs][dstV]);                                   \
        load16(vS1 + kadv, &LdsF[bs][dstV + 512]);                             \
    }

    const int niter = 2 * pi + 2;          // 64-key tiles
    const int q0 = pi * 128 + w * 32;      // wave's q base
    const int qg = q0 + l31;               // lane's q row
    const int qmax = q0 + 31;              // wave max q

    bf8 aq[4]; // Q B-frag: lane n=q=l31, k=d=step*16+hi*8+j
#pragma unroll
    for (int step = 0; step < 4; step++)
        aq[step] = *(const bf8*)(Qg + base + (size_t)qg * DMODEL +
                                 step * 16 + hi * 8);

    float lsum = 0.f;
    f32x16 oT[2] = {}; // O^T: col=q=l31, row=d=(r&3)+8(r>>2)+4hi+32*dsub

    STAGE(0, 0)
    __syncthreads(); // tile-0 DMA drained (vmcnt(0) at barrier)

    for (int kt = 0; kt < niter; kt++) {
        const int cur = kt & 1;
        if (kt + 1 < niter) STAGE(cur ^ 1, kt + 1) // flies under compute
        const u16* KB = &LdsF[cur][0];
        const u16* VB = &LdsF[cur][4096];

        const bool skipw = (kt * 64 > qmax); // wave fully above diagonal
        if (!skipw) {
            f32x16 scv[2] = {};
            __builtin_amdgcn_s_setprio(1);
#pragma unroll
            for (int step = 0; step < 4; step++)
#pragma unroll
                for (int s = 0; s < 2; s++) {
                    const int key = s * 32 + l31;
                    bf8 ak = *(const bf8*)&KB[key * 64 +
                        (((step * 2 + hi) ^ (key & 7)) * 8)];
                    scv[s] = __builtin_amdgcn_mfma_f32_32x32x16_bf16(
                        ak, aq[step], scv[s], 0, 0, 0);
                }
            __builtin_amdgcn_s_setprio(0);

            const bool masked = (kt * 64 + 63 > q0);
            const int qthr = masked ? qg : 0x7FFFFFFF;
            float pf[2][16];
#pragma unroll
            for (int s = 0; s < 2; s++) {
                const int kb2 = kt * 64 + s * 32 + 4 * hi;
#pragma unroll
                for (int r = 0; r < 16; r++) {
                    const int key = kb2 + (r & 3) + 8 * (r >> 2);
                    float pv = (key > qthr)
                                   ? 0.f
                                   : __builtin_amdgcn_exp2f(scv[s][r]);
                    pf[s][r] = pv;
                    lsum += pv;
                }
            }
            // PV: per 16-key chunk ks build P B-frag in-register, 2 MFMAs
#pragma unroll
            for (int ks = 0; ks < 4; ks++) {
                const int s = ks >> 1, c = ks & 1;
                unsigned alo, blo, ahi, bhi;
                asm("v_cvt_pk_bf16_f32 %0, %1, %2"
                    : "=v"(alo) : "v"(pf[s][8 * c + 0]), "v"(pf[s][8 * c + 1]));
                asm("v_cvt_pk_bf16_f32 %0, %1, %2"
                    : "=v"(blo) : "v"(pf[s][8 * c + 2]), "v"(pf[s][8 * c + 3]));
                asm("v_cvt_pk_bf16_f32 %0, %1, %2"
                    : "=v"(ahi) : "v"(pf[s][8 * c + 4]), "v"(pf[s][8 * c + 5]));
                asm("v_cvt_pk_bf16_f32 %0, %1, %2"
                    : "=v"(bhi) : "v"(pf[s][8 * c + 6]), "v"(pf[s][8 * c + 7]));
                asm("v_permlane32_swap_b32 %0, %1" : "+v"(alo), "+v"(ahi));
                asm("v_permlane32_swap_b32 %0, %1" : "+v"(blo), "+v"(bhi));
                union { unsigned u[4]; bf8 v; } pk;
                pk.u[0] = alo; pk.u[1] = blo; pk.u[2] = ahi; pk.u[3] = bhi;
                __builtin_amdgcn_s_setprio(1);
#pragma unroll
                for (int dsub = 0; dsub < 2; dsub++) {
                    const int d = dsub * 32 + l31;
                    bf8 av = *(const bf8*)&VB[d * 64 +
                        (((ks * 2 + hi) ^ (d & 7)) * 8)];
                    oT[dsub] = __builtin_amdgcn_mfma_f32_32x32x16_bf16(
                        av, pk.v, oT[dsub], 0, 0, 0);
                }
                __builtin_amdgcn_s_setprio(0);
            }
        }
        __syncthreads(); // reads of cur done; DMA(kt+1) drained
    }
#undef STAGE

    lsum += __shfl_xor(lsum, 32, 64); // lane pair (l31, l31+32) shares q
    const float inv = 1.f / lsum;
#pragma unroll
    for (int dsub = 0; dsub < 2; dsub++)
#pragma unroll
        for (int g = 0; g < 4; g++) {
            u16 t4[4];
#pragma unroll
            for (int m = 0; m < 4; m++)
                t4[m] = f2bf(oT[dsub][g * 4 + m] * inv);
            *(uint2*)(Og + base + (size_t)qg * DMODEL + dsub * 32 + g * 8 +
                      hi * 4) = *(uint2*)t4;
        }
}

// ---------------------------------------------------------------------------
// Workspace: d_ws 32MB = wT(8) | qb(8) | kb(8) | ob(8).
// Transients xb/vt live inside d_out (16MB), dead before O-proj writes it.
// ---------------------------------------------------------------------------
extern "C" void kernel_launch(void* const* d_in, const int* in_sizes, int n_in,
                              void* d_out, int out_size, void* d_ws, size_t ws_size,
                              hipStream_t stream) {
    const float* x  = (const float*)d_in[0];
    const float* wq = (const float*)d_in[1];
    const float* bq = (const float*)d_in[2];
    const float* wk = (const float*)d_in[3];
    const float* bk = (const float*)d_in[4];
    const float* wv = (const float*)d_in[5];
    const float* bv = (const float*)d_in[6];
    const float* wo = (const float*)d_in[7];
    const float* bo = (const float*)d_in[8];
    float* out = (float*)d_out;

    const size_t E = (size_t)MROWS * DMODEL; // 4M elems
    u16* xb  = (u16*)d_out;      // bf16 x (dead after QKV GEMM)
    u16* vt  = xb + E;           // V^T (dead after attn)
    u16* wT  = (u16*)d_ws;       // wqT|wkT|wvT|woT
    u16* woT = wT + 3145728;
    u16* qb  = wT + 4194304;
    u16* kb  = qb + E;
    u16* ob  = kb + E;

    dim3 blk(256);
    prep_kernel<<<3072, blk, 0, stream>>>(x, xb, wq, wk, wv, wo, wT);

    // fused QKV: N=3072, Q scale = log2e/8, 128x128 single-buffer m97 tiles
    gemm_mfma<0><<<dim3(24, 32), blk, 0, stream>>>(
        xb, wT, bq, bk, bv, qb, kb, vt, nullptr, 0.18033688011112042f);

    // 4-wave blocks: 128 q-rows x 64-key tiles; x = bh (32), y = pi (16)
    attn_kernel<<<dim3(BATCH * NHEADS, 16), blk, 0, stream>>>(
        qb, kb, vt, ob);

    // O-proj: 64x128 dbuf tiles (R1-verified), grid 8x64 = 2 blocks/CU
    gemm_oproj<<<dim3(8, 64), blk, 0, stream>>>(ob, woT, bo, out);
}

// Round 13
// 176.177 us; speedup vs baseline: 1.0757x; 1.0757x over previous
//
#include <hip/hip_runtime.h>
#include <math.h>

#define S_LEN 2048
#define BATCH 2
#define DMODEL 1024
#define NHEADS 16
#define MROWS 4096

typedef short bf8 __attribute__((ext_vector_type(8)));   // 8 x bf16
typedef short bf4 __attribute__((ext_vector_type(4)));   // 4 x bf16
typedef float f32x4 __attribute__((ext_vector_type(4))); // MFMA accumulator
typedef unsigned short u16;

static __device__ inline u16 f2bf(float f) {
    union { float f; unsigned u; } v; v.f = f;
    unsigned r = v.u + 0x7fffu + ((v.u >> 16) & 1u); // RNE
    return (u16)(r >> 16);
}

// async global->LDS DMA, 16B per lane. LDS dest = (wave-uniform base) + lane*16.
static __device__ inline void load16(const void* g, void* l) {
    __builtin_amdgcn_global_load_lds(
        (const __attribute__((address_space(1))) unsigned int*)g,
        (__attribute__((address_space(3))) unsigned int*)l, 16, 0, 0);
}

// ---------------------------------------------------------------------------
// Fused prep (frozen): blocks [0,2048) convert x fp32->bf16; [2048,3072)
// transpose the 4 weights to Wt[n][k] bf16.
// ---------------------------------------------------------------------------
__global__ __launch_bounds__(256) void prep_kernel(
    const float* __restrict__ x, u16* __restrict__ xb,
    const float* __restrict__ W0, const float* __restrict__ W1,
    const float* __restrict__ W2, const float* __restrict__ W3,
    u16* __restrict__ wT) {
    const int bx = blockIdx.x, t = threadIdx.x;
    if (bx < 2048) {
        int i = bx * 256 + t;
        const float4* p = (const float4*)x + (size_t)i * 2;
        float4 a = p[0], b = p[1];
        u16 tmp[8] = {f2bf(a.x), f2bf(a.y), f2bf(a.z), f2bf(a.w),
                      f2bf(b.x), f2bf(b.y), f2bf(b.z), f2bf(b.w)};
        ((uint4*)xb)[i] = *(uint4*)tmp;
        return;
    }
    __shared__ u16 Ls[64][65];
    const int id = bx - 2048;
    const int z = id >> 8, rem = id & 255;
    const int n0 = (rem & 15) * 64, k0 = (rem >> 4) * 64;
    const float* W = z == 0 ? W0 : z == 1 ? W1 : z == 2 ? W2 : W3;
    u16* Wt = wT + (size_t)z * 1024 * 1024;
    const int r = t >> 2, c4 = (t & 3) * 16;
    const float* p = W + (size_t)(k0 + r) * 1024 + n0 + c4;
#pragma unroll
    for (int i = 0; i < 16; i += 4) {
        float4 v = *(const float4*)(p + i);
        Ls[r][c4 + i + 0] = f2bf(v.x);
        Ls[r][c4 + i + 1] = f2bf(v.y);
        Ls[r][c4 + i + 2] = f2bf(v.z);
        Ls[r][c4 + i + 3] = f2bf(v.w);
    }
    __syncthreads();
    u16 tmp[16];
#pragma unroll
    for (int i = 0; i < 16; i++) tmp[i] = Ls[c4 + i][r];
    uint4* q = (uint4*)(Wt + (size_t)(n0 + r) * 1024 + k0 + c4);
    q[0] = *(uint4*)tmp;
    q[1] = *(uint4*)(tmp + 8);
}

// ---------------------------------------------------------------------------
// QKV GEMM (frozen, R9/R11-verified): m97 single-buffered 128x128, BK=64,
// global_load_lds staging, XOR-swizzled source + swizzled ds_read_b128.
// MODE 0: QKV (grid 24x32): sect 0->Q bf16*qscale, 1->K bf16, 2->V^T scatter
// ---------------------------------------------------------------------------
template <int MODE>
__global__ __launch_bounds__(256) void gemm_mfma(
    const u16* __restrict__ A, const u16* __restrict__ Bt,
    const float* __restrict__ bqp, const float* __restrict__ bkp,
    const float* __restrict__ bvp,
    u16* __restrict__ qout, u16* __restrict__ kout, u16* __restrict__ vtout,
    float* __restrict__ fout, float qscale) {
    __shared__ __align__(16) u16 As[128 * 64]; // x rows    [row][k] swizzled
    __shared__ __align__(16) u16 Bs[128 * 64]; // features  [row][k] swizzled

    const int t = threadIdx.x, lane = t & 63, w = t >> 6;
    const int quad = lane >> 4, l16 = lane & 15;
    const int wr = w >> 1, wc = w & 1; // wave quadrant: rows wr*64, cols wc*64
    const int row0 = blockIdx.y * 128, col0 = blockIdx.x * 128;
    const int K = DMODEL;

    const int srow = t >> 3;                    // 0..31
    const int ksw = ((t & 7) ^ (srow & 7)) * 8; // swizzled k offset (u16)
    const u16* ag = A + (size_t)(row0 + srow) * K + ksw;
    const u16* bg = Bt + (size_t)(col0 + srow) * K + ksw;
    const int swz = l16 & 7;

    f32x4 acc[4][4] = {}; // [mi=col frag][ni=row frag]

    u16* lA = As + (size_t)(w * 8) * 64; // wave-uniform DMA dest base
    u16* lB = Bs + (size_t)(w * 8) * 64;

    for (int it = 0; it < 16; ++it) {
        if (it) __syncthreads(); // all waves done reading LDS
        const int k0 = it * 64;
#pragma unroll
        for (int i = 0; i < 4; i++) { // 4 issues x 32 rows each, A and B
            load16(ag + (size_t)i * 32 * K + k0, lA + i * 32 * 64);
            load16(bg + (size_t)i * 32 * K + k0, lB + i * 32 * 64);
        }
        __syncthreads(); // vmcnt(0) drain: DMA landed for all waves
#pragma unroll
        for (int kc = 0; kc < 2; kc++) {
            bf8 xf[4], wf[4];
#pragma unroll
            for (int ni = 0; ni < 4; ni++)
                xf[ni] = *(const bf8*)&As[(wr * 64 + ni * 16 + l16) * 64 +
                                          ((kc * 4 + quad) ^ swz) * 8];
#pragma unroll
            for (int mi = 0; mi < 4; mi++)
                wf[mi] = *(const bf8*)&Bs[(wc * 64 + mi * 16 + l16) * 64 +
                                          ((kc * 4 + quad) ^ swz) * 8];
#pragma unroll
            for (int mi = 0; mi < 4; mi++)
#pragma unroll
                for (int ni = 0; ni < 4; ni++)
                    acc[mi][ni] = __builtin_amdgcn_mfma_f32_16x16x32_bf16(
                        wf[mi], xf[ni], acc[mi][ni], 0, 0, 0);
        }
    }

    const int sect = (col0 + wc * 64) >> 10; // uniform per wave (64-col span)
#pragma unroll
    for (int mi = 0; mi < 4; mi++) {
        const int featb = col0 + wc * 64 + mi * 16 + quad * 4;
        float b4[4];
#pragma unroll
        for (int reg = 0; reg < 4; reg++)
            b4[reg] = (MODE == 1 ? bqp : (sect == 0 ? bqp : sect == 1 ? bkp : bvp))
                          [(featb + reg) & 1023];
#pragma unroll
        for (int ni = 0; ni < 4; ni++) {
            const int xrow = row0 + wr * 64 + ni * 16 + l16;
            if (MODE == 1) {
                float4 o;
                o.x = acc[mi][ni][0] + b4[0];
                o.y = acc[mi][ni][1] + b4[1];
                o.z = acc[mi][ni][2] + b4[2];
                o.w = acc[mi][ni][3] + b4[3];
                *(float4*)(fout + (size_t)xrow * 1024 + featb) = o;
            } else {
                const int cf = featb & 1023;
                if (sect == 0) {
                    u16 t4[4];
#pragma unroll
                    for (int reg = 0; reg < 4; reg++)
                        t4[reg] = f2bf((acc[mi][ni][reg] + b4[reg]) * qscale);
                    *(uint2*)(qout + (size_t)xrow * 1024 + cf) = *(uint2*)t4;
                } else if (sect == 1) {
                    u16 t4[4];
#pragma unroll
                    for (int reg = 0; reg < 4; reg++)
                        t4[reg] = f2bf(acc[mi][ni][reg] + b4[reg]);
                    *(uint2*)(kout + (size_t)xrow * 1024 + cf) = *(uint2*)t4;
                } else { // V^T: Vt[(xrow>>11)*1024 + f][xrow&2047]
#pragma unroll
                    for (int reg = 0; reg < 4; reg++)
                        vtout[((size_t)(xrow >> 11) * 1024 + cf + reg) * S_LEN +
                              (xrow & 2047)] = f2bf(acc[mi][ni][reg] + b4[reg]);
                }
            }
        }
    }
}

// ---------------------------------------------------------------------------
// O-proj GEMM (frozen, R11-verified): 64x128 dbuf tiles, grid 8x64.
// ---------------------------------------------------------------------------
__global__ __launch_bounds__(256) void gemm_oproj(
    const u16* __restrict__ A, const u16* __restrict__ Bt,
    const float* __restrict__ bop, float* __restrict__ fout) {
    __shared__ __align__(16) u16 As[2][64 * 64];  // x rows
    __shared__ __align__(16) u16 Bs[2][128 * 64]; // W rows (features)

    const int t = threadIdx.x, lane = t & 63, w = t >> 6;
    const int quad = lane >> 4, l16 = lane & 15;
    const int row0 = blockIdx.y * 64, col0 = blockIdx.x * 128;
    const int K = DMODEL;

    const int lrow = lane >> 3;               // 0..7
    const int koff = ((lane & 7) ^ lrow) * 8; // swizzled k-group (global side)
    const u16* ag = A + (size_t)(row0 + w * 16 + lrow) * K + koff;
    const u16* bg = Bt + (size_t)(col0 + w * 32 + lrow) * K + koff;
    const int swz = l16 & 7;

    f32x4 acc[2][4] = {};

    // prologue: stage k0=0 into buffer 0
    {
        u16* lA = As[0] + (w * 16) * 64;
        u16* lB = Bs[0] + (w * 32) * 64;
        load16(ag, lA);
        load16(ag + (size_t)8 * K, lA + 512);
#pragma unroll
        for (int d = 0; d < 4; d++)
            load16(bg + (size_t)d * 8 * K, lB + d * 512);
    }

#pragma unroll 2
    for (int it = 0; it < 16; it++) {
        const int buf = it & 1;
        __syncthreads(); // current buf's DMA landed; prior reads of other buf done
        if (it + 1 < 16) { // prefetch next k-slab into the other buffer
            const int k0 = (it + 1) * 64;
            u16* lA = As[buf ^ 1] + (w * 16) * 64;
            u16* lB = Bs[buf ^ 1] + (w * 32) * 64;
            load16(ag + k0, lA);
            load16(ag + (size_t)8 * K + k0, lA + 512);
#pragma unroll
            for (int d = 0; d < 4; d++)
                load16(bg + (size_t)d * 8 * K + k0, lB + d * 512);
        }
#pragma unroll
        for (int kc = 0; kc < 2; kc++) {
            bf8 xf[4], wf[2];
#pragma unroll
            for (int ni = 0; ni < 4; ni++)
                xf[ni] = *(const bf8*)&As[buf][(ni * 16 + l16) * 64 +
                                              ((kc * 4 + quad) ^ swz) * 8];
#pragma unroll
            for (int mi = 0; mi < 2; mi++)
                wf[mi] = *(const bf8*)&Bs[buf][(w * 32 + mi * 16 + l16) * 64 +
                                              ((kc * 4 + quad) ^ swz) * 8];
#pragma unroll
            for (int mi = 0; mi < 2; mi++)
#pragma unroll
                for (int ni = 0; ni < 4; ni++)
                    acc[mi][ni] = __builtin_amdgcn_mfma_f32_16x16x32_bf16(
                        wf[mi], xf[ni], acc[mi][ni], 0, 0, 0);
        }
    }

#pragma unroll
    for (int mi = 0; mi < 2; mi++) {
        const int featb = col0 + w * 32 + mi * 16 + quad * 4;
        float b4[4];
#pragma unroll
        for (int reg = 0; reg < 4; reg++)
            b4[reg] = bop[(featb + reg) & 1023];
#pragma unroll
        for (int ni = 0; ni < 4; ni++) {
            const int xrow = row0 + ni * 16 + l16;
            float4 o;
            o.x = acc[mi][ni][0] + b4[0];
            o.y = acc[mi][ni][1] + b4[1];
            o.z = acc[mi][ni][2] + b4[2];
            o.w = acc[mi][ni][3] + b4[3];
            *(float4*)(fout + (size_t)xrow * 1024 + featb) = o;
        }
    }
}

// ---------------------------------------------------------------------------
// R13 flash attention: R9-exact structure (verified 44.4us — R12's 32x32
// restructure halved LDS conflicts but lost on occupancy/VALU, reverted).
// ONLY change: balanced causal pairing. Linear block id = bh + 32*y, so CU c
// receives blocks with y0 and y0+8. Old map pi=15-y gave pair work
// (16-y0)+(8-y0) = 8..22 tile-units (2.4x imbalance, makespan set by the
// 22s). New map pi = y<8 ? 15-y : y-8 gives every pair (pi)+(15-pi) -> 17
// units constant. Zero register/code-structure cost.
// ---------------------------------------------------------------------------
__global__ __launch_bounds__(512, 4) void attn_kernel(
    const u16* __restrict__ Qg, const u16* __restrict__ Kg,
    const u16* __restrict__ Vt, u16* __restrict__ Og) {
    // [buf][ K: pl(2) x row(128) x 32u16 | V: kb2(4) x d(64) x 32u16 ]
    __shared__ __align__(16) u16 LdsF[2 * 16384]; // 64KB

    const int t = threadIdx.x, lane = t & 63, w = t >> 6;
    const int quad = lane >> 4, l16 = lane & 15;
    const int wtile = w >> 2, wq = w & 3;
    const int y = blockIdx.y;
    const int pi = (y < 8) ? (15 - y) : (y - 8); // balanced heavy+light pairs
    const int bh = blockIdx.x, b = bh >> 4, h = bh & 15;
    const size_t base = (size_t)b * S_LEN * DMODEL + h * 64;
    const size_t vbase = ((size_t)b * 1024 + h * 64) * S_LEN;
    const int swz = (l16 >> 1) & 3;

    // ---- DMA staging setup: waves 0-3 stage K, waves 4-7 stage V ----
    const int rK = lane >> 2, cc = lane & 3;
    const int ssS = (rK >> 1) & 3;
    const int chnk = (cc ^ ssS) * 8; // swizzled-source u16 offset
    const u16* src;
    size_t jstr, tstr;
    if (w < 4) {
        src = Kg + base + (size_t)((w & 1) * 64 + rK) * DMODEL +
              (w >> 1) * 32 + chnk;
        jstr = (size_t)16 * DMODEL;
        tstr = (size_t)128 * DMODEL;
    } else {
        const int wv = w - 4;
        src = Vt + vbase + (size_t)rK * S_LEN +
              (wv >> 1) * 64 + (wv & 1) * 32 + chnk;
        jstr = (size_t)16 * S_LEN;
        tstr = (size_t)128;
    }
    const int dstoff = (w * 4) * 512; // u16; wave-uniform

#define STAGE(bufsel, tile)                                                    \
    {                                                                          \
        u16* _d = LdsF + (bufsel) * 16384 + dstoff;                            \
        const u16* _s = src + (size_t)(tile) * tstr;                           \
        load16(_s, _d);                                                        \
        load16(_s + jstr, _d + 512);                                           \
        load16(_s + 2 * jstr, _d + 1024);                                      \
        load16(_s + 3 * jstr, _d + 1536);                                      \
    }

    const int niter = pi + 1;              // 128-key tiles
    const int q0 = pi * 128 + wtile * 64;  // this wave's 64-row q-tile base

    bf8 aq[2]; // Q-frag (B-operand: lane n=q=l16, k=d=c*32+quad*8+j)
#pragma unroll
    for (int c = 0; c < 2; c++)
        aq[c] = *(const bf8*)(Qg + base +
            (size_t)(q0 + wq * 16 + l16) * DMODEL + c * 32 + quad * 8);

    float lsum = 0.f;    // per-lane: q = l16
    f32x4 oT[4] = {};    // O^T: col=q=l16, row=d=ds*16+quad*4+reg

    const int qloc = wtile * 64 + wq * 16 + l16; // 0..127 within q-block
    const int qmax = wtile * 64 + wq * 16 + 15;  // wave-uniform max q-row

    STAGE(0, 0)
    __syncthreads(); // drain tile-0 DMA (compiler emits vmcnt(0) before barrier)

    for (int kt = 0; kt < niter; kt++) {
        const int cur = kt & 1;
        if (kt + 1 < niter) STAGE(cur ^ 1, kt + 1) // overlaps this tile's compute
        const u16* KB = LdsF + cur * 16384;
        const u16* VB = KB + 8192;

        f32x4 scv[8] = {};
        __builtin_amdgcn_s_setprio(1);
#pragma unroll
        for (int c = 0; c < 2; c++)
#pragma unroll
            for (int ns = 0; ns < 8; ns++) {
                bf8 ak = *(const bf8*)&KB[(c * 128 + ns * 16 + l16) * 32 +
                                          ((quad ^ swz) * 8)];
                scv[ns] = __builtin_amdgcn_mfma_f32_16x16x32_bf16(
                    ak, aq[c], scv[ns], 0, 0, 0);
            }
        __builtin_amdgcn_s_setprio(0);

        const bool diag = (kt == niter - 1);
#pragma unroll
        for (int ns = 0; ns < 8; ns++) {
            // wave-uniform skip: fully-masked ns-blocks on the diag tile
            if (diag && ns * 16 > qmax) continue;
            float p[4];
#pragma unroll
            for (int r = 0; r < 4; r++) {
                int key = ns * 16 + quad * 4 + r; // 0..127 within kv-tile
                p[r] = (diag && key > qloc) ? 0.f
                                            : __builtin_amdgcn_exp2f(scv[ns][r]);
                lsum += p[r];
            }
            union { unsigned u[2]; bf4 v; } pk;
            pk.u[0] = (__float_as_uint(p[0]) >> 16) |
                      (__float_as_uint(p[1]) & 0xffff0000u);
            pk.u[1] = (__float_as_uint(p[2]) >> 16) |
                      (__float_as_uint(p[3]) & 0xffff0000u);
            __builtin_amdgcn_s_setprio(1);
#pragma unroll
            for (int ds = 0; ds < 4; ds++) {
                bf4 av = *(const bf4*)&VB[((ns >> 1) * 64 + ds * 16 + l16) * 32 +
                    ((((ns & 1) * 2 + (quad >> 1)) ^ swz) * 8) + (quad & 1) * 4];
                oT[ds] = __builtin_amdgcn_mfma_f32_16x16x16bf16_1k(
                    av, pk.v, oT[ds], 0, 0, 0);
            }
            __builtin_amdgcn_s_setprio(0);
        }
        __syncthreads(); // all waves done reading cur; DMA(kt+1) drained
    }
#undef STAGE

    float l = lsum;
    l += __shfl_xor(l, 16, 64);
    l += __shfl_xor(l, 32, 64);
    const float inv = 1.f / l;
    const int qq = q0 + wq * 16 + l16;
#pragma unroll
    for (int ds = 0; ds < 4; ds++) {
        u16 t4[4];
#pragma unroll
        for (int r = 0; r < 4; r++) t4[r] = f2bf(oT[ds][r] * inv);
        *(uint2*)(Og + base + (size_t)qq * DMODEL + ds * 16 + quad * 4) =
            *(uint2*)t4;
    }
}

// ---------------------------------------------------------------------------
// Workspace: d_ws 32MB = wT(8) | qb(8) | kb(8) | ob(8).
// Transients xb/vt live inside d_out (16MB), dead before O-proj writes it.
// ---------------------------------------------------------------------------
extern "C" void kernel_launch(void* const* d_in, const int* in_sizes, int n_in,
                              void* d_out, int out_size, void* d_ws, size_t ws_size,
                              hipStream_t stream) {
    const float* x  = (const float*)d_in[0];
    const float* wq = (const float*)d_in[1];
    const float* bq = (const float*)d_in[2];
    const float* wk = (const float*)d_in[3];
    const float* bk = (const float*)d_in[4];
    const float* wv = (const float*)d_in[5];
    const float* bv = (const float*)d_in[6];
    const float* wo = (const float*)d_in[7];
    const float* bo = (const float*)d_in[8];
    float* out = (float*)d_out;

    const size_t E = (size_t)MROWS * DMODEL; // 4M elems
    u16* xb  = (u16*)d_out;      // bf16 x (dead after QKV GEMM)
    u16* vt  = xb + E;           // V^T (dead after attn)
    u16* wT  = (u16*)d_ws;       // wqT|wkT|wvT|woT
    u16* woT = wT + 3145728;
    u16* qb  = wT + 4194304;
    u16* kb  = qb + E;
    u16* ob  = kb + E;

    dim3 blk(256);
    prep_kernel<<<3072, blk, 0, stream>>>(x, xb, wq, wk, wv, wo, wT);

    // fused QKV: N=3072, Q scale = log2e/8, 128x128 single-buffer m97 tiles
    gemm_mfma<0><<<dim3(24, 32), blk, 0, stream>>>(
        xb, wT, bq, bk, bv, qb, kb, vt, nullptr, 0.18033688011112042f);

    // 8-wave blocks: 128 q-rows x 128-key tiles; x = bh (32), y = pi-order
    attn_kernel<<<dim3(BATCH * NHEADS, 16), dim3(512), 0, stream>>>(
        qb, kb, vt, ob);

    // O-proj: 64x128 dbuf tiles (R1-verified), grid 8x64 = 2 blocks/CU
    gemm_oproj<<<dim3(8, 64), blk, 0, stream>>>(ob, woT, bo, out);
}